// Round 4
// baseline (363.437 us; speedup 1.0000x reference)
//
#include <hip/hip_runtime.h>
#include <math.h>

#define BN    16
#define NGTC  32
#define NB    4096      // 12-bit value buckets: float_bits >> 20
#define BSH   20
#define BLK   256
#define GX    64        // k_main blocks per batch row
#define CNTSH 40        // count field shift in packed u64 histogram
#define FPS   1048576.0f // 2^20 fixed-point scale for packed sum

struct Accum {
  unsigned int npos[BN];
  float pos_sum;
  float box_sum;
  float hard[BN];
};

__device__ inline float wred_sum_f(float v) {
#pragma unroll
  for (int o = 32; o > 0; o >>= 1) v += __shfl_down(v, o, 64);
  return v;
}
__device__ inline unsigned wred_sum_u(unsigned v) {
#pragma unroll
  for (int o = 32; o > 0; o >>= 1) v += __shfl_down(v, o, 64);
  return v;
}
__device__ inline float sl1(float d) {
  float ad = fabsf(d);
  return ad < 1.f ? 0.5f * d * d : ad - 0.5f;
}
// Must be the SAME code in k_main and k_fix so corrections cancel bit-exactly.
__device__ inline float boxterm(float4 av, float4 g, float4 p) {
  float acx = (av.x + av.z) * 0.5f, acy = (av.y + av.w) * 0.5f;
  float aw = av.z - av.x, ah = av.w - av.y;
  float gcx = (g.x + g.z) * 0.5f, gcy = (g.y + g.w) * 0.5f;
  float gw = g.z - g.x, gh = g.w - g.y;
  float t0 = (gcx - acx) / (aw / 10.f);
  float t1 = (gcy - acy) / (ah / 10.f);
  float t2 = __logf(gw / aw) * 5.f;
  float t3 = __logf(gh / ah) * 5.f;
  return sl1(p.x - t0) + sl1(p.y - t1) + sl1(p.z - t2) + sl1(p.w - t3);
}

// Fused pass: per-anchor argmax (division-free) + threshold pos/neg losses +
// packed LDS histogram of negative BCE + per-(b,gt) partial argmax keys.
// Forced-match corrections are applied later by k_fix.
__global__ __launch_bounds__(BLK, 4) void k_main(
    const float* __restrict__ labels, const float4* __restrict__ poffs,
    const float4* __restrict__ anchors, const float4* __restrict__ gt,
    Accum* __restrict__ acc, unsigned long long* __restrict__ partial,
    unsigned int* __restrict__ ghc, float* __restrict__ ghs, int A) {
  __shared__ unsigned long long hist[NB];   // (count << 40) | fixedpoint-sum
  __shared__ unsigned long long sbest[NGTC];
  __shared__ float4 sgt[NGTC];
  __shared__ float  sarea[NGTC];
  __shared__ float sredf[BLK / 64], sredb[BLK / 64];
  __shared__ unsigned sredu[BLK / 64];
  int b = blockIdx.y, t = threadIdx.x;
  for (int i = t; i < NB; i += BLK) hist[i] = 0ull;
  if (t < NGTC) {
    float4 g = gt[b * NGTC + t];
    sgt[t] = g;
    sarea[t] = (g.z - g.x) * (g.w - g.y);
    sbest[t] = 0ull;
  }
  __syncthreads();

  float psum = 0.f, bsum = 0.f;
  unsigned cnt = 0u;
  int rot = t & 31;
  for (int a = blockIdx.x * BLK + t; a < A; a += GX * BLK) {
    float4 av = anchors[a];
    float area_a = (av.z - av.x) * (av.w - av.y);
    float bn = -1.f, bd = 1.f;    // best iou = bn/bd, division-free compare
    int gid = 0;
#pragma unroll
    for (int jj = 0; jj < NGTC; ++jj) {
      int j = (jj + rot) & 31;    // stagger lanes across LDS slots
      float4 g = sgt[j];
      float w = fminf(av.z, g.z) - fmaxf(av.x, g.x);
      float h = fminf(av.w, g.w) - fmaxf(av.y, g.y);
      w = fmaxf(w, 0.f); h = fmaxf(h, 0.f);
      float inter = w * h;
      float dj = area_a + sarea[j] - inter;
      if (inter * bd > bn * dj) { bn = inter; bd = dj; gid = j; }
      if (inter > 0.f) {
        unsigned long long key =
            (((unsigned long long)__float_as_uint(inter / dj)) << 32) |
            (unsigned)(~(unsigned)a);
        atomicMax(&sbest[j], key);
      }
    }
    bool pos = bn > 0.3f * bd;
    float x = labels[(size_t)b * A + a];
    float e = __expf(-fabsf(x));
    float sp = fmaxf(x, 0.f) + __logf(1.f + e);   // softplus = bce(y=0)
    if (pos) {
      cnt++; psum += sp - x;                       // bce(y=1)
      float4 p = poffs[(size_t)b * A + a];
      bsum += boxterm(av, sgt[gid], p);
    } else {
      unsigned bk = __float_as_uint(sp) >> BSH;
      atomicAdd(&hist[bk],
                (1ull << CNTSH) + (unsigned long long)(unsigned)(sp * FPS + 0.5f));
    }
  }
  __syncthreads();
  if (t < NGTC)
    partial[(size_t)blockIdx.x * (BN * NGTC) + b * NGTC + t] = sbest[t];

  psum = wred_sum_f(psum);
  bsum = wred_sum_f(bsum);
  cnt  = wred_sum_u(cnt);
  int wid = t >> 6, lane = t & 63;
  if (lane == 0) { sredf[wid] = psum; sredb[wid] = bsum; sredu[wid] = cnt; }
  __syncthreads();
  if (t == 0) {
    float ps = 0.f, bs = 0.f; unsigned c = 0;
#pragma unroll
    for (int w2 = 0; w2 < BLK / 64; ++w2) { ps += sredf[w2]; bs += sredb[w2]; c += sredu[w2]; }
    if (c) atomicAdd(&acc->npos[b], c);
    atomicAdd(&acc->pos_sum, ps);
    atomicAdd(&acc->box_sum, bs);
  }
  for (int i = t; i < NB; i += BLK) {
    unsigned long long pk = hist[i];
    if (pk) {
      atomicAdd(&ghc[(size_t)b * NB + i], (unsigned)(pk >> CNTSH));
      atomicAdd(&ghs[(size_t)b * NB + i],
                (float)(pk & ((1ull << CNTSH) - 1ull)) * (1.f / FPS));
    }
  }
}

// Reduce partial keys, resolve duplicate best-anchors (last j wins), and apply
// forced-match corrections to npos/pos_sum/box_sum and the neg histogram.
__global__ __launch_bounds__(512) void k_fix(
    const float* __restrict__ labels, const float4* __restrict__ poffs,
    const float4* __restrict__ anchors, const float4* __restrict__ gt,
    Accum* __restrict__ acc, const unsigned long long* __restrict__ partial,
    unsigned int* __restrict__ ghc, float* __restrict__ ghs, int A) {
  __shared__ unsigned sa[BN * NGTC];
  int t = threadIdx.x;               // one thread per (b, j)
  int b = t >> 5, j = t & 31;
  unsigned long long best = 0ull;
  for (int i = 0; i < GX; ++i) {
    unsigned long long v = partial[(size_t)i * (BN * NGTC) + t];
    best = v > best ? v : best;
  }
  if (best == 0ull) best = 0xFFFFFFFFull;  // no overlap anywhere -> anchor 0
  unsigned a = ~(unsigned)(best & 0xFFFFFFFFull);
  sa[t] = a;
  __syncthreads();
  bool winner = true;
  for (int j2 = j + 1; j2 < NGTC; ++j2)
    if (sa[(b << 5) | j2] == a) { winner = false; break; }
  if (!winner) return;  // duplicate: a later j owns this anchor

  // Replicate k_main's per-anchor pass for anchor a EXACTLY (same rotation).
  float4 av = anchors[a];
  float area_a = (av.z - av.x) * (av.w - av.y);
  int rot = (int)(a & 31u);   // k_main thread owning a had t = a % BLK
  float bn = -1.f, bd = 1.f;
  int gid = 0;
  for (int jj = 0; jj < NGTC; ++jj) {
    int j2 = (jj + rot) & 31;
    float4 g = gt[b * NGTC + j2];
    float w = fminf(av.z, g.z) - fmaxf(av.x, g.x);
    float h = fminf(av.w, g.w) - fmaxf(av.y, g.y);
    w = fmaxf(w, 0.f); h = fmaxf(h, 0.f);
    float inter = w * h;
    float dj = area_a + (g.z - g.x) * (g.w - g.y) - inter;
    if (inter * bd > bn * dj) { bn = inter; bd = dj; gid = j2; }
  }
  bool tpos = bn > 0.3f * bd;
  float4 p = poffs[(size_t)b * A + a];
  float newbox = boxterm(av, gt[b * NGTC + j], p);
  if (tpos) {
    if (gid != j) {   // box target overridden: swap terms
      float oldbox = boxterm(av, gt[b * NGTC + gid], p);
      atomicAdd(&acc->box_sum, newbox - oldbox);
    }
  } else {            // was counted negative: promote to positive
    float x = labels[(size_t)b * A + a];
    float e = __expf(-fabsf(x));
    float sp = fmaxf(x, 0.f) + __logf(1.f + e);
    atomicAdd(&acc->npos[b], 1u);
    atomicAdd(&acc->pos_sum, sp - x);
    atomicAdd(&acc->box_sum, newbox);
    unsigned bk = __float_as_uint(sp) >> BSH;
    atomicSub(&ghc[(size_t)b * NB + bk], 1u);
    atomicAdd(&ghs[(size_t)b * NB + bk], -sp);
  }
}

// Per-row suffix-select top-(3*n_pos) from count+sum histograms.
__global__ __launch_bounds__(BLK) void k_sel(Accum* __restrict__ acc,
                                             const unsigned int* __restrict__ ghc,
                                             const float* __restrict__ ghs) {
  int b = blockIdx.x, t = threadIdx.x;
  __shared__ unsigned cc[BLK];
  __shared__ float    cs[BLK];
  const unsigned* c = ghc + (size_t)b * NB;
  const float*    s = ghs + (size_t)b * NB;
  const int CH = NB / BLK;   // 16 buckets per thread-chunk
  unsigned cm = 0; float sm = 0.f;
  int base = t * CH;
  for (int i = 0; i < CH; ++i) { cm += c[base + i]; sm += s[base + i]; }
  cc[t] = cm; cs[t] = sm;
  __syncthreads();
  if (t == 0) {
    unsigned k = 3u * acc->npos[b];
    unsigned cum = 0; float hard = 0.f; int cb = -1;
    for (int q = BLK - 1; q >= 0; --q) {
      if (cum + cc[q] >= k) { cb = q; break; }
      cum += cc[q]; hard += cs[q];
    }
    if (cb >= 0) {
      for (int u = CH - 1; u >= 0; --u) {
        int bk = cb * CH + u;
        unsigned c2 = c[bk];
        if (cum + c2 >= k) {
          unsigned r = k - cum;
          if (c2 && r) {
            float m  = s[bk] / (float)c2;
            float lo = __uint_as_float((unsigned)bk << BSH);
            float hi = __uint_as_float((unsigned)(bk + 1) << BSH);
            // uniform-within-bucket model for top-r sum; exact at r==c2
            hard += (float)r * m +
                    (float)r * (float)(c2 - r) * (hi - lo) / (2.f * (float)c2);
          }
          break;
        }
        cum += c2; hard += s[bk];
      }
    }
    acc->hard[b] = hard;
  }
}

__global__ void k_final(const Accum* __restrict__ acc, float* __restrict__ out) {
  if (threadIdx.x == 0 && blockIdx.x == 0) {
    unsigned npt = 0;
    for (int b = 0; b < BN; ++b) npt += acc->npos[b];
    float hard = 0.f;
    for (int b = 0; b < BN; ++b) hard += acc->hard[b];
    float npf = (float)npt;
    float box = acc->box_sum / (npf * 4.f);
    float cls = (hard + acc->pos_sum) / npf;
    out[0] = box + cls;
    out[1] = box;
    out[2] = cls;
  }
}

extern "C" void kernel_launch(void* const* d_in, const int* in_sizes, int n_in,
                              void* d_out, int out_size, void* d_ws, size_t ws_size,
                              hipStream_t stream) {
  const float*  labels  = (const float*)d_in[0];
  const float4* poffs   = (const float4*)d_in[1];
  const float4* anchors = (const float4*)d_in[2];
  const float4* gt      = (const float4*)d_in[3];
  int A = in_sizes[2] / 4;  // 100000

  char* ws = (char*)d_ws;
  Accum* acc = (Accum*)ws;
  size_t off_hc = (sizeof(Accum) + 255) & ~(size_t)255;
  unsigned int* ghc = (unsigned int*)(ws + off_hc);
  size_t off_hs = off_hc + (size_t)BN * NB * sizeof(unsigned int);
  float* ghs = (float*)(ws + off_hs);
  size_t off_part = off_hs + (size_t)BN * NB * sizeof(float);
  unsigned long long* partial = (unsigned long long*)(ws + off_part);
  // partial (GX*BN*NGTC u64 = 256 KB) is fully written by k_main; no memset.

  hipMemsetAsync(ws, 0, off_part, stream);  // Accum + both histograms (~516 KB)

  dim3 grid(GX, BN);
  k_main<<<grid, BLK, 0, stream>>>(labels, poffs, anchors, gt, acc, partial, ghc, ghs, A);
  k_fix<<<1, 512, 0, stream>>>(labels, poffs, anchors, gt, acc, partial, ghc, ghs, A);
  k_sel<<<BN, BLK, 0, stream>>>(acc, ghc, ghs);
  k_final<<<1, 64, 0, stream>>>(acc, (float*)d_out);
}

// Round 5
// 183.815 us; speedup vs baseline: 1.9772x; 1.9772x over previous
//
#include <hip/hip_runtime.h>
#include <math.h>

#define BN    16
#define NGTC  32
#define NB    4096      // 12-bit value buckets: float_bits >> 20
#define BSH   20
#define BLK   256
#define GX    64        // k_main blocks per batch row
#define CNTSH 40        // count field shift in packed u64 histogram
#define FPS   1048576.0f // 2^20 fixed-point scale for packed sum

struct Accum {
  unsigned int npos[BN];
  float pos_sum;
  float box_sum;
  float hard[BN];
};

__device__ inline float wred_sum_f(float v) {
#pragma unroll
  for (int o = 32; o > 0; o >>= 1) v += __shfl_down(v, o, 64);
  return v;
}
__device__ inline unsigned wred_sum_u(unsigned v) {
#pragma unroll
  for (int o = 32; o > 0; o >>= 1) v += __shfl_down(v, o, 64);
  return v;
}
__device__ inline float sl1(float d) {
  float ad = fabsf(d);
  return ad < 1.f ? 0.5f * d * d : ad - 0.5f;
}
// Must be the SAME code in k_main and k_fix so corrections cancel bit-exactly.
__device__ inline float boxterm(float4 av, float4 g, float4 p) {
  float acx = (av.x + av.z) * 0.5f, acy = (av.y + av.w) * 0.5f;
  float aw = av.z - av.x, ah = av.w - av.y;
  float gcx = (g.x + g.z) * 0.5f, gcy = (g.y + g.w) * 0.5f;
  float gw = g.z - g.x, gh = g.w - g.y;
  float t0 = (gcx - acx) / (aw / 10.f);
  float t1 = (gcy - acy) / (ah / 10.f);
  float t2 = __logf(gw / aw) * 5.f;
  float t3 = __logf(gh / ah) * 5.f;
  return sl1(p.x - t0) + sl1(p.y - t1) + sl1(p.z - t2) + sl1(p.w - t3);
}

// Fused pass: per-anchor argmax (division-free) + threshold pos/neg losses +
// packed LDS histogram of negative BCE + per-(b,gt) partial argmax keys.
// Forced-match corrections are applied later by k_fix.
// NOTE: no min-waves in launch_bounds — forcing 4 waves/EU capped VGPR at 64
// and spilled ~500B/anchor-iter to scratch (618MB FETCH, 6x slowdown, R4).
__global__ __launch_bounds__(BLK) void k_main(
    const float* __restrict__ labels, const float4* __restrict__ poffs,
    const float4* __restrict__ anchors, const float4* __restrict__ gt,
    Accum* __restrict__ acc, unsigned long long* __restrict__ partial,
    unsigned int* __restrict__ ghc, float* __restrict__ ghs, int A) {
  __shared__ unsigned long long hist[NB];   // (count << 40) | fixedpoint-sum
  __shared__ unsigned long long sbest[NGTC];
  __shared__ float4 sgt[NGTC];
  __shared__ float  sarea[NGTC];
  __shared__ float sredf[BLK / 64], sredb[BLK / 64];
  __shared__ unsigned sredu[BLK / 64];
  int b = blockIdx.y, t = threadIdx.x;
  for (int i = t; i < NB; i += BLK) hist[i] = 0ull;
  if (t < NGTC) {
    float4 g = gt[b * NGTC + t];
    sgt[t] = g;
    sarea[t] = (g.z - g.x) * (g.w - g.y);
    sbest[t] = 0ull;
  }
  __syncthreads();

  float psum = 0.f, bsum = 0.f;
  unsigned cnt = 0u;
  int rot = t & 31;
  for (int a = blockIdx.x * BLK + t; a < A; a += GX * BLK) {
    float4 av = anchors[a];
    float area_a = (av.z - av.x) * (av.w - av.y);
    float bn = -1.f, bd = 1.f;    // best iou = bn/bd, division-free compare
    int gid = 0;
#pragma unroll
    for (int jj = 0; jj < NGTC; ++jj) {
      int j = (jj + rot) & 31;    // stagger lanes across LDS slots
      float4 g = sgt[j];
      float w = fminf(av.z, g.z) - fmaxf(av.x, g.x);
      float h = fminf(av.w, g.w) - fmaxf(av.y, g.y);
      w = fmaxf(w, 0.f); h = fmaxf(h, 0.f);
      float inter = w * h;
      float dj = area_a + sarea[j] - inter;
      if (inter * bd > bn * dj) { bn = inter; bd = dj; gid = j; }
      if (inter > 0.f) {
        float iou = inter * __builtin_amdgcn_rcpf(dj);  // approx rcp: ordering key only
        unsigned long long key =
            (((unsigned long long)__float_as_uint(iou)) << 32) |
            (unsigned)(~(unsigned)a);
        // guard: skip the DS-atomic RMW when we can't win (most of the time)
        if (key > *(volatile unsigned long long*)&sbest[j])
          atomicMax(&sbest[j], key);
      }
    }
    bool pos = bn > 0.3f * bd;
    float x = labels[(size_t)b * A + a];
    float e = __expf(-fabsf(x));
    float sp = fmaxf(x, 0.f) + __logf(1.f + e);   // softplus = bce(y=0)
    if (pos) {
      cnt++; psum += sp - x;                       // bce(y=1)
      float4 p = poffs[(size_t)b * A + a];
      bsum += boxterm(av, sgt[gid], p);
    } else {
      unsigned bk = __float_as_uint(sp) >> BSH;
      atomicAdd(&hist[bk],
                (1ull << CNTSH) + (unsigned long long)(unsigned)(sp * FPS + 0.5f));
    }
  }
  __syncthreads();
  if (t < NGTC)
    partial[(size_t)blockIdx.x * (BN * NGTC) + b * NGTC + t] = sbest[t];

  psum = wred_sum_f(psum);
  bsum = wred_sum_f(bsum);
  cnt  = wred_sum_u(cnt);
  int wid = t >> 6, lane = t & 63;
  if (lane == 0) { sredf[wid] = psum; sredb[wid] = bsum; sredu[wid] = cnt; }
  __syncthreads();
  if (t == 0) {
    float ps = 0.f, bs = 0.f; unsigned c = 0;
#pragma unroll
    for (int w2 = 0; w2 < BLK / 64; ++w2) { ps += sredf[w2]; bs += sredb[w2]; c += sredu[w2]; }
    if (c) atomicAdd(&acc->npos[b], c);
    atomicAdd(&acc->pos_sum, ps);
    atomicAdd(&acc->box_sum, bs);
  }
  for (int i = t; i < NB; i += BLK) {
    unsigned long long pk = hist[i];
    if (pk) {
      atomicAdd(&ghc[(size_t)b * NB + i], (unsigned)(pk >> CNTSH));
      atomicAdd(&ghs[(size_t)b * NB + i],
                (float)(pk & ((1ull << CNTSH) - 1ull)) * (1.f / FPS));
    }
  }
}

// Reduce partial keys, resolve duplicate best-anchors (last j wins), and apply
// forced-match corrections to npos/pos_sum/box_sum and the neg histogram.
__global__ __launch_bounds__(512) void k_fix(
    const float* __restrict__ labels, const float4* __restrict__ poffs,
    const float4* __restrict__ anchors, const float4* __restrict__ gt,
    Accum* __restrict__ acc, const unsigned long long* __restrict__ partial,
    unsigned int* __restrict__ ghc, float* __restrict__ ghs, int A) {
  __shared__ unsigned sa[BN * NGTC];
  int t = threadIdx.x;               // one thread per (b, j)
  int b = t >> 5, j = t & 31;
  unsigned long long best = 0ull;
  for (int i = 0; i < GX; ++i) {
    unsigned long long v = partial[(size_t)i * (BN * NGTC) + t];
    best = v > best ? v : best;
  }
  if (best == 0ull) best = 0xFFFFFFFFull;  // no overlap anywhere -> anchor 0
  unsigned a = ~(unsigned)(best & 0xFFFFFFFFull);
  sa[t] = a;
  __syncthreads();
  bool winner = true;
  for (int j2 = j + 1; j2 < NGTC; ++j2)
    if (sa[(b << 5) | j2] == a) { winner = false; break; }
  if (!winner) return;  // duplicate: a later j owns this anchor

  // Replicate k_main's per-anchor pass for anchor a EXACTLY (same rotation).
  float4 av = anchors[a];
  float area_a = (av.z - av.x) * (av.w - av.y);
  int rot = (int)(a & 31u);   // k_main thread owning a had t = a % BLK
  float bn = -1.f, bd = 1.f;
  int gid = 0;
  for (int jj = 0; jj < NGTC; ++jj) {
    int j2 = (jj + rot) & 31;
    float4 g = gt[b * NGTC + j2];
    float w = fminf(av.z, g.z) - fmaxf(av.x, g.x);
    float h = fminf(av.w, g.w) - fmaxf(av.y, g.y);
    w = fmaxf(w, 0.f); h = fmaxf(h, 0.f);
    float inter = w * h;
    float dj = area_a + (g.z - g.x) * (g.w - g.y) - inter;
    if (inter * bd > bn * dj) { bn = inter; bd = dj; gid = j2; }
  }
  bool tpos = bn > 0.3f * bd;
  float4 p = poffs[(size_t)b * A + a];
  float newbox = boxterm(av, gt[b * NGTC + j], p);
  if (tpos) {
    if (gid != j) {   // box target overridden: swap terms
      float oldbox = boxterm(av, gt[b * NGTC + gid], p);
      atomicAdd(&acc->box_sum, newbox - oldbox);
    }
  } else {            // was counted negative: promote to positive
    float x = labels[(size_t)b * A + a];
    float e = __expf(-fabsf(x));
    float sp = fmaxf(x, 0.f) + __logf(1.f + e);
    atomicAdd(&acc->npos[b], 1u);
    atomicAdd(&acc->pos_sum, sp - x);
    atomicAdd(&acc->box_sum, newbox);
    unsigned bk = __float_as_uint(sp) >> BSH;
    atomicSub(&ghc[(size_t)b * NB + bk], 1u);
    atomicAdd(&ghs[(size_t)b * NB + bk], -sp);
  }
}

// Per-row suffix-select top-(3*n_pos) from count+sum histograms.
__global__ __launch_bounds__(BLK) void k_sel(Accum* __restrict__ acc,
                                             const unsigned int* __restrict__ ghc,
                                             const float* __restrict__ ghs) {
  int b = blockIdx.x, t = threadIdx.x;
  __shared__ unsigned cc[BLK];
  __shared__ float    cs[BLK];
  const unsigned* c = ghc + (size_t)b * NB;
  const float*    s = ghs + (size_t)b * NB;
  const int CH = NB / BLK;   // 16 buckets per thread-chunk
  unsigned cm = 0; float sm = 0.f;
  int base = t * CH;
  for (int i = 0; i < CH; ++i) { cm += c[base + i]; sm += s[base + i]; }
  cc[t] = cm; cs[t] = sm;
  __syncthreads();
  if (t == 0) {
    unsigned k = 3u * acc->npos[b];
    unsigned cum = 0; float hard = 0.f; int cb = -1;
    for (int q = BLK - 1; q >= 0; --q) {
      if (cum + cc[q] >= k) { cb = q; break; }
      cum += cc[q]; hard += cs[q];
    }
    if (cb >= 0) {
      for (int u = CH - 1; u >= 0; --u) {
        int bk = cb * CH + u;
        unsigned c2 = c[bk];
        if (cum + c2 >= k) {
          unsigned r = k - cum;
          if (c2 && r) {
            float m  = s[bk] / (float)c2;
            float lo = __uint_as_float((unsigned)bk << BSH);
            float hi = __uint_as_float((unsigned)(bk + 1) << BSH);
            // uniform-within-bucket model for top-r sum; exact at r==c2
            hard += (float)r * m +
                    (float)r * (float)(c2 - r) * (hi - lo) / (2.f * (float)c2);
          }
          break;
        }
        cum += c2; hard += s[bk];
      }
    }
    acc->hard[b] = hard;
  }
}

__global__ void k_final(const Accum* __restrict__ acc, float* __restrict__ out) {
  if (threadIdx.x == 0 && blockIdx.x == 0) {
    unsigned npt = 0;
    for (int b = 0; b < BN; ++b) npt += acc->npos[b];
    float hard = 0.f;
    for (int b = 0; b < BN; ++b) hard += acc->hard[b];
    float npf = (float)npt;
    float box = acc->box_sum / (npf * 4.f);
    float cls = (hard + acc->pos_sum) / npf;
    out[0] = box + cls;
    out[1] = box;
    out[2] = cls;
  }
}

extern "C" void kernel_launch(void* const* d_in, const int* in_sizes, int n_in,
                              void* d_out, int out_size, void* d_ws, size_t ws_size,
                              hipStream_t stream) {
  const float*  labels  = (const float*)d_in[0];
  const float4* poffs   = (const float4*)d_in[1];
  const float4* anchors = (const float4*)d_in[2];
  const float4* gt      = (const float4*)d_in[3];
  int A = in_sizes[2] / 4;  // 100000

  char* ws = (char*)d_ws;
  Accum* acc = (Accum*)ws;
  size_t off_hc = (sizeof(Accum) + 255) & ~(size_t)255;
  unsigned int* ghc = (unsigned int*)(ws + off_hc);
  size_t off_hs = off_hc + (size_t)BN * NB * sizeof(unsigned int);
  float* ghs = (float*)(ws + off_hs);
  size_t off_part = off_hs + (size_t)BN * NB * sizeof(float);
  unsigned long long* partial = (unsigned long long*)(ws + off_part);
  // partial (GX*BN*NGTC u64 = 256 KB) is fully written by k_main; no memset.

  hipMemsetAsync(ws, 0, off_part, stream);  // Accum + both histograms (~516 KB)

  dim3 grid(GX, BN);
  k_main<<<grid, BLK, 0, stream>>>(labels, poffs, anchors, gt, acc, partial, ghc, ghs, A);
  k_fix<<<1, 512, 0, stream>>>(labels, poffs, anchors, gt, acc, partial, ghc, ghs, A);
  k_sel<<<BN, BLK, 0, stream>>>(acc, ghc, ghs);
  k_final<<<1, 64, 0, stream>>>(acc, (float*)d_out);
}

// Round 6
// 103.553 us; speedup vs baseline: 3.5097x; 1.7751x over previous
//
#include <hip/hip_runtime.h>
#include <math.h>

#define BN    16
#define NGTC  32
#define NB    4096      // 12-bit value buckets: float_bits >> 20
#define BSH   20
#define BLK   256
#define GX    64        // k_main blocks per batch row
#define CNTSH 40        // count field shift in packed u64 histogram
#define FPS   1048576.0f // 2^20 fixed-point scale for packed sum

struct Accum {
  unsigned int npos[BN];
  float pos_sum;
  float box_sum;
  float hard[BN];
};

__device__ inline float wred_sum_f(float v) {
#pragma unroll
  for (int o = 32; o > 0; o >>= 1) v += __shfl_down(v, o, 64);
  return v;
}
__device__ inline unsigned wred_sum_u(unsigned v) {
#pragma unroll
  for (int o = 32; o > 0; o >>= 1) v += __shfl_down(v, o, 64);
  return v;
}
__device__ inline float sl1(float d) {
  float ad = fabsf(d);
  return ad < 1.f ? 0.5f * d * d : ad - 0.5f;
}
// Must be the SAME code in k_main and k_fix so corrections cancel bit-exactly.
__device__ inline float boxterm(float4 av, float4 g, float4 p) {
  float acx = (av.x + av.z) * 0.5f, acy = (av.y + av.w) * 0.5f;
  float aw = av.z - av.x, ah = av.w - av.y;
  float gcx = (g.x + g.z) * 0.5f, gcy = (g.y + g.w) * 0.5f;
  float gw = g.z - g.x, gh = g.w - g.y;
  float t0 = (gcx - acx) / (aw / 10.f);
  float t1 = (gcy - acy) / (ah / 10.f);
  float t2 = __logf(gw / aw) * 5.f;
  float t3 = __logf(gh / ah) * 5.f;
  return sl1(p.x - t0) + sl1(p.y - t1) + sl1(p.z - t2) + sl1(p.w - t3);
}

// Fused pass: per-anchor argmax (division-free) + threshold pos/neg losses +
// packed LDS histogram of negative BCE + per-(b,gt) partial argmax keys.
// Forced-match corrections are applied later by k_fix.
// NOTES (measured): (1) no min-waves in launch_bounds — forcing 4 waves/EU
// capped VGPR at 64 and spilled ~500B/anchor-iter (618MB FETCH, R4).
// (2) no read-guard on the LDS atomicMax — a volatile ds_read dependency
// stalled every iteration ~120cyc at low occupancy (162us, R5). Fire-and-
// forget ds_atomic is tracked by lgkmcnt only and pipelines freely.
// (3) unroll capped at 8, 2 anchors/thread: full 32x unroll hit 176 VGPR
// -> 2 waves/SIMD -> 10% occupancy (R5).
__global__ __launch_bounds__(BLK) void k_main(
    const float* __restrict__ labels, const float4* __restrict__ poffs,
    const float4* __restrict__ anchors, const float4* __restrict__ gt,
    Accum* __restrict__ acc, unsigned long long* __restrict__ partial,
    unsigned int* __restrict__ ghc, float* __restrict__ ghs, int A) {
  __shared__ unsigned long long hist[NB];   // (count << 40) | fixedpoint-sum
  __shared__ unsigned long long sbest[NGTC];
  __shared__ float4 sgt[NGTC];
  __shared__ float  sarea[NGTC];
  __shared__ float sredf[BLK / 64], sredb[BLK / 64];
  __shared__ unsigned sredu[BLK / 64];
  int b = blockIdx.y, t = threadIdx.x;
  for (int i = t; i < NB; i += BLK) hist[i] = 0ull;
  if (t < NGTC) {
    float4 g = gt[b * NGTC + t];
    sgt[t] = g;
    sarea[t] = (g.z - g.x) * (g.w - g.y);
    sbest[t] = 0ull;
  }
  __syncthreads();

  float psum = 0.f, bsum = 0.f;
  unsigned cnt = 0u;
  int rot = t & 31;
  for (int a0 = blockIdx.x * (2 * BLK) + t; a0 < A; a0 += GX * 2 * BLK) {
    int a1 = a0 + BLK;
    bool v1 = a1 < A;
    float4 av0 = anchors[a0];
    float4 av1 = v1 ? anchors[a1] : make_float4(0.f, 0.f, 0.f, 0.f);
    float area0 = (av0.z - av0.x) * (av0.w - av0.y);
    float area1 = (av1.z - av1.x) * (av1.w - av1.y);
    float bn0 = -1.f, bd0 = 1.f, bn1 = -1.f, bd1 = 1.f;
    int gid0 = 0, gid1 = 0;
#pragma unroll 8
    for (int jj = 0; jj < NGTC; ++jj) {
      int j = (jj + rot) & 31;    // stagger lanes across LDS slots
      float4 g = sgt[j];
      float sa_ = sarea[j];
      float w0 = fmaxf(fminf(av0.z, g.z) - fmaxf(av0.x, g.x), 0.f);
      float h0 = fmaxf(fminf(av0.w, g.w) - fmaxf(av0.y, g.y), 0.f);
      float i0 = w0 * h0;
      float d0 = area0 + sa_ - i0;
      if (i0 * bd0 > bn0 * d0) { bn0 = i0; bd0 = d0; gid0 = j; }
      float w1 = fmaxf(fminf(av1.z, g.z) - fmaxf(av1.x, g.x), 0.f);
      float h1 = fmaxf(fminf(av1.w, g.w) - fmaxf(av1.y, g.y), 0.f);
      float i1 = w1 * h1;
      float d1 = area1 + sa_ - i1;
      if (i1 * bd1 > bn1 * d1) { bn1 = i1; bd1 = d1; gid1 = j; }
      if (i0 > 0.f) {
        float iou = i0 * __builtin_amdgcn_rcpf(d0);  // ordering key only
        atomicMax(&sbest[j],
                  (((unsigned long long)__float_as_uint(iou)) << 32) |
                  (unsigned)(~(unsigned)a0));
      }
      if (v1 && i1 > 0.f) {
        float iou = i1 * __builtin_amdgcn_rcpf(d1);
        atomicMax(&sbest[j],
                  (((unsigned long long)__float_as_uint(iou)) << 32) |
                  (unsigned)(~(unsigned)a1));
      }
    }
#pragma unroll
    for (int q = 0; q < 2; ++q) {
      int a = q ? a1 : a0;
      if (q && !v1) break;
      float4 av = q ? av1 : av0;
      float bn = q ? bn1 : bn0, bd = q ? bd1 : bd0;
      int gid = q ? gid1 : gid0;
      bool pos = bn > 0.3f * bd;
      float x = labels[(size_t)b * A + a];
      float e = __expf(-fabsf(x));
      float sp = fmaxf(x, 0.f) + __logf(1.f + e);   // softplus = bce(y=0)
      if (pos) {
        cnt++; psum += sp - x;                       // bce(y=1)
        float4 p = poffs[(size_t)b * A + a];
        bsum += boxterm(av, sgt[gid], p);
      } else {
        unsigned bk = __float_as_uint(sp) >> BSH;
        atomicAdd(&hist[bk],
                  (1ull << CNTSH) + (unsigned long long)(unsigned)(sp * FPS + 0.5f));
      }
    }
  }
  __syncthreads();
  if (t < NGTC)
    partial[(size_t)blockIdx.x * (BN * NGTC) + b * NGTC + t] = sbest[t];

  psum = wred_sum_f(psum);
  bsum = wred_sum_f(bsum);
  cnt  = wred_sum_u(cnt);
  int wid = t >> 6, lane = t & 63;
  if (lane == 0) { sredf[wid] = psum; sredb[wid] = bsum; sredu[wid] = cnt; }
  __syncthreads();
  if (t == 0) {
    float ps = 0.f, bs = 0.f; unsigned c = 0;
#pragma unroll
    for (int w2 = 0; w2 < BLK / 64; ++w2) { ps += sredf[w2]; bs += sredb[w2]; c += sredu[w2]; }
    if (c) atomicAdd(&acc->npos[b], c);
    atomicAdd(&acc->pos_sum, ps);
    atomicAdd(&acc->box_sum, bs);
  }
  for (int i = t; i < NB; i += BLK) {
    unsigned long long pk = hist[i];
    if (pk) {
      atomicAdd(&ghc[(size_t)b * NB + i], (unsigned)(pk >> CNTSH));
      atomicAdd(&ghs[(size_t)b * NB + i],
                (float)(pk & ((1ull << CNTSH) - 1ull)) * (1.f / FPS));
    }
  }
}

// Reduce partial keys, resolve duplicate best-anchors (last j wins), and apply
// forced-match corrections to npos/pos_sum/box_sum and the neg histogram.
__global__ __launch_bounds__(512) void k_fix(
    const float* __restrict__ labels, const float4* __restrict__ poffs,
    const float4* __restrict__ anchors, const float4* __restrict__ gt,
    Accum* __restrict__ acc, const unsigned long long* __restrict__ partial,
    unsigned int* __restrict__ ghc, float* __restrict__ ghs, int A) {
  __shared__ unsigned sa[BN * NGTC];
  int t = threadIdx.x;               // one thread per (b, j)
  int b = t >> 5, j = t & 31;
  unsigned long long best = 0ull;
  for (int i = 0; i < GX; ++i) {
    unsigned long long v = partial[(size_t)i * (BN * NGTC) + t];
    best = v > best ? v : best;
  }
  if (best == 0ull) best = 0xFFFFFFFFull;  // no overlap anywhere -> anchor 0
  unsigned a = ~(unsigned)(best & 0xFFFFFFFFull);
  sa[t] = a;
  __syncthreads();
  bool winner = true;
  for (int j2 = j + 1; j2 < NGTC; ++j2)
    if (sa[(b << 5) | j2] == a) { winner = false; break; }
  if (!winner) return;  // duplicate: a later j owns this anchor

  // Replicate k_main's per-anchor pass for anchor a EXACTLY (same rotation,
  // same op order, same division-free compare).
  float4 av = anchors[a];
  float area_a = (av.z - av.x) * (av.w - av.y);
  int rot = (int)(a & 31u);   // a == t (mod 256) in k_main, so rot = a & 31
  float bn = -1.f, bd = 1.f;
  int gid = 0;
  for (int jj = 0; jj < NGTC; ++jj) {
    int j2 = (jj + rot) & 31;
    float4 g = gt[b * NGTC + j2];
    float w = fmaxf(fminf(av.z, g.z) - fmaxf(av.x, g.x), 0.f);
    float h = fmaxf(fminf(av.w, g.w) - fmaxf(av.y, g.y), 0.f);
    float inter = w * h;
    float dj = area_a + (g.z - g.x) * (g.w - g.y) - inter;
    if (inter * bd > bn * dj) { bn = inter; bd = dj; gid = j2; }
  }
  bool tpos = bn > 0.3f * bd;
  float4 p = poffs[(size_t)b * A + a];
  float newbox = boxterm(av, gt[b * NGTC + j], p);
  if (tpos) {
    if (gid != j) {   // box target overridden: swap terms
      float oldbox = boxterm(av, gt[b * NGTC + gid], p);
      atomicAdd(&acc->box_sum, newbox - oldbox);
    }
  } else {            // was counted negative: promote to positive
    float x = labels[(size_t)b * A + a];
    float e = __expf(-fabsf(x));
    float sp = fmaxf(x, 0.f) + __logf(1.f + e);
    atomicAdd(&acc->npos[b], 1u);
    atomicAdd(&acc->pos_sum, sp - x);
    atomicAdd(&acc->box_sum, newbox);
    unsigned bk = __float_as_uint(sp) >> BSH;
    atomicSub(&ghc[(size_t)b * NB + bk], 1u);
    atomicAdd(&ghs[(size_t)b * NB + bk], -sp);
  }
}

// Per-row suffix-select top-(3*n_pos) from count+sum histograms.
__global__ __launch_bounds__(BLK) void k_sel(Accum* __restrict__ acc,
                                             const unsigned int* __restrict__ ghc,
                                             const float* __restrict__ ghs) {
  int b = blockIdx.x, t = threadIdx.x;
  __shared__ unsigned cc[BLK];
  __shared__ float    cs[BLK];
  const unsigned* c = ghc + (size_t)b * NB;
  const float*    s = ghs + (size_t)b * NB;
  const int CH = NB / BLK;   // 16 buckets per thread-chunk
  unsigned cm = 0; float sm = 0.f;
  int base = t * CH;
  for (int i = 0; i < CH; ++i) { cm += c[base + i]; sm += s[base + i]; }
  cc[t] = cm; cs[t] = sm;
  __syncthreads();
  if (t == 0) {
    unsigned k = 3u * acc->npos[b];
    unsigned cum = 0; float hard = 0.f; int cb = -1;
    for (int q = BLK - 1; q >= 0; --q) {
      if (cum + cc[q] >= k) { cb = q; break; }
      cum += cc[q]; hard += cs[q];
    }
    if (cb >= 0) {
      for (int u = CH - 1; u >= 0; --u) {
        int bk = cb * CH + u;
        unsigned c2 = c[bk];
        if (cum + c2 >= k) {
          unsigned r = k - cum;
          if (c2 && r) {
            float m  = s[bk] / (float)c2;
            float lo = __uint_as_float((unsigned)bk << BSH);
            float hi = __uint_as_float((unsigned)(bk + 1) << BSH);
            // uniform-within-bucket model for top-r sum; exact at r==c2
            hard += (float)r * m +
                    (float)r * (float)(c2 - r) * (hi - lo) / (2.f * (float)c2);
          }
          break;
        }
        cum += c2; hard += s[bk];
      }
    }
    acc->hard[b] = hard;
  }
}

__global__ void k_final(const Accum* __restrict__ acc, float* __restrict__ out) {
  if (threadIdx.x == 0 && blockIdx.x == 0) {
    unsigned npt = 0;
    for (int b = 0; b < BN; ++b) npt += acc->npos[b];
    float hard = 0.f;
    for (int b = 0; b < BN; ++b) hard += acc->hard[b];
    float npf = (float)npt;
    float box = acc->box_sum / (npf * 4.f);
    float cls = (hard + acc->pos_sum) / npf;
    out[0] = box + cls;
    out[1] = box;
    out[2] = cls;
  }
}

extern "C" void kernel_launch(void* const* d_in, const int* in_sizes, int n_in,
                              void* d_out, int out_size, void* d_ws, size_t ws_size,
                              hipStream_t stream) {
  const float*  labels  = (const float*)d_in[0];
  const float4* poffs   = (const float4*)d_in[1];
  const float4* anchors = (const float4*)d_in[2];
  const float4* gt      = (const float4*)d_in[3];
  int A = in_sizes[2] / 4;  // 100000

  char* ws = (char*)d_ws;
  Accum* acc = (Accum*)ws;
  size_t off_hc = (sizeof(Accum) + 255) & ~(size_t)255;
  unsigned int* ghc = (unsigned int*)(ws + off_hc);
  size_t off_hs = off_hc + (size_t)BN * NB * sizeof(unsigned int);
  float* ghs = (float*)(ws + off_hs);
  size_t off_part = off_hs + (size_t)BN * NB * sizeof(float);
  unsigned long long* partial = (unsigned long long*)(ws + off_part);
  // partial (GX*BN*NGTC u64 = 256 KB) is fully written by k_main; no memset.

  hipMemsetAsync(ws, 0, off_part, stream);  // Accum + both histograms (~516 KB)

  dim3 grid(GX, BN);
  k_main<<<grid, BLK, 0, stream>>>(labels, poffs, anchors, gt, acc, partial, ghc, ghs, A);
  k_fix<<<1, 512, 0, stream>>>(labels, poffs, anchors, gt, acc, partial, ghc, ghs, A);
  k_sel<<<BN, BLK, 0, stream>>>(acc, ghc, ghs);
  k_final<<<1, 64, 0, stream>>>(acc, (float*)d_out);
}